// Round 2
// baseline (341.376 us; speedup 1.0000x reference)
//
#include <hip/hip_runtime.h>
#include <hip/hip_bf16.h>

// out[k, s] = sum over genes g with seq_idx[g]==k of exp(A[gi,s] + 1 - pos[g]*B[gi,s])
// N=1000 genomes, S=32 samples, M=2M genes, K=100k sequences.
//
// Round 2: counting-sort genes by seq into CSR (payload {pos, gidx}), then
// segmented register reduction -> zero f32 atomics (round 1 was bound at
// ~310G atomics/s by 64M f32 atomicAdds; WRITE_SIZE showed 256 MB of atomic
// write-through traffic).

#define SCAN_CHUNK 1024

// ---- pass 1: histogram of seq_idx -----------------------------------------
__global__ __launch_bounds__(256) void hist_kernel(
    const int* __restrict__ sidx, int* __restrict__ cnt, int M)
{
    int i = blockIdx.x * blockDim.x + threadIdx.x;
    const int stride = gridDim.x * blockDim.x;
    for (; i < M; i += stride) atomicAdd(&cnt[sidx[i]], 1);
}

// ---- pass 2a: per-chunk sums ----------------------------------------------
__global__ __launch_bounds__(256) void scan_partial_kernel(
    const int* __restrict__ cnt, int* __restrict__ partial, int K)
{
    __shared__ int sm[256];
    const int base = blockIdx.x * SCAN_CHUNK;
    int sum = 0;
    for (int j = threadIdx.x; j < SCAN_CHUNK; j += 256) {
        const int idx = base + j;
        sum += (idx < K) ? cnt[idx] : 0;
    }
    sm[threadIdx.x] = sum;
    __syncthreads();
    for (int d = 128; d > 0; d >>= 1) {
        if (threadIdx.x < d) sm[threadIdx.x] += sm[threadIdx.x + d];
        __syncthreads();
    }
    if (threadIdx.x == 0) partial[blockIdx.x] = sm[0];
}

// ---- pass 2b: exclusive scan of chunk sums (NB <= 256) --------------------
__global__ __launch_bounds__(256) void scan_top_kernel(int* __restrict__ partial, int NB)
{
    __shared__ int sm[256];
    const int t = threadIdx.x;
    const int v = (t < NB) ? partial[t] : 0;
    sm[t] = v;
    __syncthreads();
    for (int d = 1; d < 256; d <<= 1) {
        const int x = (t >= d) ? sm[t - d] : 0;
        __syncthreads();
        sm[t] += x;
        __syncthreads();
    }
    if (t < NB) partial[t] = sm[t] - v;   // exclusive prefix
}

// ---- pass 2c: per-chunk exclusive scan + base -> off[], cur[] -------------
__global__ __launch_bounds__(256) void scan_chunk_kernel(
    const int* __restrict__ cnt, const int* __restrict__ partial,
    int* __restrict__ off, int* __restrict__ cur, int K)
{
    __shared__ int sm[256];
    const int t = threadIdx.x;
    const int i0 = blockIdx.x * SCAN_CHUNK + t * 4;
    int v[4];
    int s = 0;
#pragma unroll
    for (int j = 0; j < 4; j++) {
        v[j] = (i0 + j < K) ? cnt[i0 + j] : 0;
        s += v[j];
    }
    sm[t] = s;
    __syncthreads();
    for (int d = 1; d < 256; d <<= 1) {
        const int x = (t >= d) ? sm[t - d] : 0;
        __syncthreads();
        sm[t] += x;
        __syncthreads();
    }
    int run = partial[blockIdx.x] + ((t > 0) ? sm[t - 1] : 0);
#pragma unroll
    for (int j = 0; j < 4; j++) {
        if (i0 + j < K) { off[i0 + j] = run; cur[i0 + j] = run; }
        run += v[j];
    }
}

// ---- pass 3: scatter genes into CSR order ---------------------------------
__global__ __launch_bounds__(256) void scatter_kernel(
    const float* __restrict__ pos, const int* __restrict__ gidx,
    const int* __restrict__ sidx, int* __restrict__ cur,
    int2* __restrict__ payload, int M)
{
    int i = blockIdx.x * blockDim.x + threadIdx.x;
    const int stride = gridDim.x * blockDim.x;
    for (; i < M; i += stride) {
        const int s = sidx[i];
        const int slot = atomicAdd(&cur[s], 1);
        int2 pl;
        pl.x = __float_as_int(pos[i]);
        pl.y = gidx[i];
        payload[slot] = pl;
    }
}

// ---- pass 4: segmented reduction, one 32-lane group per sequence ----------
__global__ __launch_bounds__(256) void reduce_kernel(
    const float* __restrict__ A, const float* __restrict__ B,
    const int2* __restrict__ payload, const int* __restrict__ off,
    const int* __restrict__ cnt, float* __restrict__ out, int K)
{
    const int lane = threadIdx.x & 31;                               // sample s
    const int grp = (int)((blockIdx.x * blockDim.x + threadIdx.x) >> 5);  // sequence k
    if (grp >= K) return;
    const int start = off[grp];   // same addr across the 32-lane group -> broadcast
    const int n = cnt[grp];
    float acc = 0.0f;
    for (int j = 0; j < n; j++) {
        const int2 pl = payload[start + j];        // broadcast 8B
        const float p = __int_as_float(pl.x);
        const int gi = pl.y;
        const float a = A[(gi << 5) + lane];       // 128B coalesced, L2-resident
        const float b = B[(gi << 5) + lane];
        acc += __expf(fmaf(-p, b, a + 1.0f));
    }
    out[(grp << 5) + lane] = acc;                  // single coalesced store
}

// ---- fallback (round-1 atomic version) if workspace too small -------------
__global__ __launch_bounds__(256) void scatter_exp_fallback(
    const float* __restrict__ A, const float* __restrict__ B,
    const float* __restrict__ pos, const int* __restrict__ gidx,
    const int* __restrict__ sidx, float* __restrict__ out, int M)
{
    const int lane = threadIdx.x & 31;
    int group = (int)((blockIdx.x * blockDim.x + threadIdx.x) >> 5);
    const int stride = (int)((gridDim.x * blockDim.x) >> 5);
    for (int g = group; g < M; g += stride) {
        const int gi = gidx[g];
        const int si = sidx[g];
        const float p = pos[g];
        const float a = A[(gi << 5) + lane];
        const float b = B[(gi << 5) + lane];
        atomicAdd(&out[(si << 5) + lane], __expf(fmaf(-p, b, a + 1.0f)));
    }
}

extern "C" void kernel_launch(void* const* d_in, const int* in_sizes, int n_in,
                              void* d_out, int out_size, void* d_ws, size_t ws_size,
                              hipStream_t stream)
{
    const float* A    = (const float*)d_in[0];   // [N,32]
    const float* B    = (const float*)d_in[1];   // [N,32]
    const float* pos  = (const float*)d_in[2];   // [M]
    const int*   gidx = (const int*)d_in[3];     // [M]
    const int*   sidx = (const int*)d_in[4];     // [M]
    float*       out  = (float*)d_out;           // [K,32]

    const int M = in_sizes[2];
    const int K = out_size / 32;
    const int NB = (K + SCAN_CHUNK - 1) / SCAN_CHUNK;   // 98 for K=100k

    // workspace layout: cnt[K] | off[K] | cur[K] | partial[256] | payload[M] (int2)
    char* ws = (char*)d_ws;
    int* cnt = (int*)ws;
    int* off = cnt + K;
    int* cur = off + K;
    int* partial = cur + K;
    size_t head = (((size_t)(3 * K + 256)) * sizeof(int) + 15) & ~(size_t)15;
    int2* payload = (int2*)(ws + head);
    const size_t need = head + (size_t)M * sizeof(int2);

    if (ws_size < need || NB > 256) {
        // fallback: atomic scatter (correct, slower)
        hipMemsetAsync(d_out, 0, (size_t)out_size * sizeof(float), stream);
        scatter_exp_fallback<<<8192, 256, 0, stream>>>(A, B, pos, gidx, sidx, out, M);
        return;
    }

    hipMemsetAsync(cnt, 0, (size_t)K * sizeof(int), stream);
    hist_kernel<<<2048, 256, 0, stream>>>(sidx, cnt, M);
    scan_partial_kernel<<<NB, 256, 0, stream>>>(cnt, partial, K);
    scan_top_kernel<<<1, 256, 0, stream>>>(partial, NB);
    scan_chunk_kernel<<<NB, 256, 0, stream>>>(cnt, partial, off, cur, K);
    scatter_kernel<<<2048, 256, 0, stream>>>(pos, gidx, sidx, cur, payload, M);
    reduce_kernel<<<(K + 7) / 8, 256, 0, stream>>>(A, B, payload, off, cnt, out, K);
}